// Round 4
// baseline (163.343 us; speedup 1.0000x reference)
//
#include <hip/hip_runtime.h>

namespace {
constexpr int NB   = 16;
constexpr int NC   = 64;
constexpr int HW   = 128*128;
constexpr int SL   = 16384;
constexpr int NG   = 8;
constexpr int CQ   = 64;
constexpr int NCH  = SL/CQ;   // 256
constexpr int WCH  = 4;       // chunks (waves) per block

__device__ __forceinline__ float frcp(float x){ return __builtin_amdgcn_rcpf(x); }
__device__ __forceinline__ float rl(float v, int s){
  return __int_as_float(__builtin_amdgcn_readlane(__float_as_int(v), s));
}
__device__ __forceinline__ float sigu(float a){ return frcp(1.0f + __expf(-a)); }

__global__ __launch_bounds__(256) void k_tok(
    const float* __restrict__ x, const float* __restrict__ w_tok,
    const float* __restrict__ b_tok, float* __restrict__ g0)
{
  long idx = (long)blockIdx.x * 256 + threadIdx.x;
  int b = (int)(idx >> 14);
  int l = (int)(idx & (SL-1));
  float acc[8];
  #pragma unroll
  for (int g = 0; g < 8; ++g) acc[g] = b_tok[g];
  const float* xp = x + (long)b*NC*HW + l;
  #pragma unroll 8
  for (int c = 0; c < NC; ++c) {
    float v = xp[(long)c*HW];
    #pragma unroll
    for (int g = 0; g < 8; ++g) acc[g] += v * w_tok[g*NC + c];   // uniform -> s_load
  }
  float* gp = g0 + idx*8;
  *(float4*)gp     = make_float4(acc[0],acc[1],acc[2],acc[3]);
  *(float4*)(gp+4) = make_float4(acc[4],acc[5],acc[6],acc[7]);
}

// PASS 0: per-chunk state contribution Sc + decay Pc.  PASS 1: outputs -> gf.
template<int PASS>
__global__ __launch_bounds__(256)
__attribute__((amdgpu_waves_per_eu(4, 4)))
void k_chunk(
    const float* __restrict__ g0, const float* __restrict__ w_in,
    const float* __restrict__ w_conv, const float* __restrict__ b_conv,
    const float* __restrict__ dt_bias, const float* __restrict__ A_log,
    const float* __restrict__ Dvec, const float* __restrict__ norm_w,
    const float* __restrict__ w_out,
    float* __restrict__ Sc, float* __restrict__ Pc,
    const float* __restrict__ Stin, float* __restrict__ gf)
{
  constexpr int JMAX = (PASS==1) ? 48 : 32;      // PASS0 needs x,B only
  __shared__ float s_big[(PASS==0) ? WCH*CQ*36 : 1];

  int tid = threadIdx.x, lane = tid & 63, wave = tid >> 6;
  int b   = blockIdx.x >> 6;
  int chB = (blockIdx.x & 63)*WCH + wave;
  long cg = (long)b*NCH + chB;
  int l0  = chB*CQ;
  long pos = (long)b*SL + l0 + lane;

  // own u (coalesced)
  float u[8];
  { const float* up = g0 + pos*8;
    float4 a = *(const float4*)up, c = *(const float4*)(up+4);
    u[0]=a.x;u[1]=a.y;u[2]=a.z;u[3]=a.w;u[4]=c.x;u[5]=c.y;u[6]=c.z;u[7]=c.w; }

  // stage incoming state into regs early (PASS1)
  float sv[4] = {0.f,0.f,0.f,0.f};
  if constexpr (PASS==1) {
    float4 t = *(const float4*)(Stin + cg*256 + lane*4);
    sv[0]=t.x; sv[1]=t.y; sv[2]=t.z; sv[3]=t.w;
  }

  // ---- halo pre-values in registers (no LDS, no barrier) ----
  // hA: lane = p*32 + j   (p in {0,1} = pos l0-2+p, j in 0..31)
  // hB: lane = p*16 + (j-32)  for j in 32..47 (PASS1 only; lanes 0..31)
  float hA = 0.f, hB = 0.f;
  {
    int pA = lane >> 5, jA = lane & 31;
    int hlA = l0 - 2 + pA;
    float uA[8] = {0,0,0,0,0,0,0,0};
    if (hlA >= 0) {
      const float* hp2 = g0 + ((long)b*SL + hlA)*8;
      float4 a = *(const float4*)hp2, c = *(const float4*)(hp2+4);
      uA[0]=a.x;uA[1]=a.y;uA[2]=a.z;uA[3]=a.w;uA[4]=c.x;uA[5]=c.y;uA[6]=c.z;uA[7]=c.w;
    }
    #pragma unroll
    for (int g = 0; g < 8; ++g) hA += uA[g]*w_in[(16+jA)*8+g];
    if constexpr (PASS==1) {
      int pB = (lane >> 4) & 1, jB = 32 + (lane & 15);
      int hlB = l0 - 2 + pB;
      float uB[8] = {0,0,0,0,0,0,0,0};
      if (hlB >= 0) {
        const float* hp2 = g0 + ((long)b*SL + hlB)*8;
        float4 a = *(const float4*)hp2, c = *(const float4*)(hp2+4);
        uB[0]=a.x;uB[1]=a.y;uB[2]=a.z;uB[3]=a.w;uB[4]=c.x;uB[5]=c.y;uB[6]=c.z;uB[7]=c.w;
      }
      #pragma unroll
      for (int g = 0; g < 8; ++g) hB += uB[g]*w_in[(16+jB)*8+g];
    }
  }

  // ---- blocked in-proj + causal conv + silu (weights via s_load) ----
  float xv[16], Bv[16];
  float Cvr[(PASS==1) ? 16 : 1];
  #pragma unroll
  for (int jb = 0; jb < JMAX/8; ++jb) {
    float pr[8];
    #pragma unroll
    for (int jj = 0; jj < 8; ++jj) {
      int j = jb*8 + jj;
      float a = 0.f;
      #pragma unroll
      for (int g = 0; g < 8; ++g) a += u[g]*w_in[(16+j)*8+g];   // uniform -> s_load
      pr[jj] = a;
    }
    #pragma unroll
    for (int jj = 0; jj < 8; ++jj) {
      int j = jb*8 + jj;
      float pm1 = __shfl_up(pr[jj], 1);
      float pm2 = __shfl_up(pr[jj], 2);
      float h0j = (j < 32) ? rl(hA, j)      : rl(hB, j-32);
      float h1j = (j < 32) ? rl(hA, 32+j)   : rl(hB, 16+(j-32));
      pm1 = (lane == 0) ? h1j : pm1;
      pm2 = (lane == 0) ? h0j : ((lane == 1) ? h1j : pm2);
      float a = b_conv[j] + pm2*w_conv[j*3] + pm1*w_conv[j*3+1] + pr[jj]*w_conv[j*3+2];
      float s = a * sigu(a);
      if (j < 16) xv[j] = s;
      else if (j < 32) Bv[j-16] = s;
      else { if constexpr (PASS==1) Cvr[j-32] = s; }
    }
  }

  // ---- dt (softplus) + cumsum of A*dt via shuffle prefix ----
  float dt0, dt1;
  { float a = dt_bias[0];
    #pragma unroll
    for (int g = 0; g < 8; ++g) a += u[g]*w_in[64*8+g];
    dt0 = (a > 20.f) ? a : log1pf(__expf(a));
    float b2 = dt_bias[1];
    #pragma unroll
    for (int g = 0; g < 8; ++g) b2 += u[g]*w_in[65*8+g];
    dt1 = (b2 > 20.f) ? b2 : log1pf(__expf(b2)); }
  float A0 = -__expf(A_log[0]), A1 = -__expf(A_log[1]);
  float c0 = A0*dt0, c1 = A1*dt1;
  #pragma unroll
  for (int off = 1; off < 64; off <<= 1) {
    float t0 = __shfl_up(c0, off), t1 = __shfl_up(c1, off);
    if (lane >= off) { c0 += t0; c1 += t1; }
  }
  float ce0 = __expf(c0), ce1 = __expf(c1);
  float cf0 = __expf(-c0)*dt0, cf1 = __expf(-c1)*dt1;
  float cee0 = rl(ce0, 63), cee1 = rl(ce1, 63);

  if constexpr (PASS==0) {
    float* slab = &s_big[wave*CQ*36 + lane*36];
    #pragma unroll
    for (int k = 0; k < 16; ++k) { slab[k] = xv[k]; slab[16+k] = Bv[k]; }
    slab[32] = cee0*cf0; slab[33] = cee1*cf1;
    __builtin_amdgcn_wave_barrier();
    int hp = lane >> 2, nb = lane & 3, h = hp >> 3;
    float a0=0.f, a1=0.f, a2=0.f, a3=0.f;
    const float* base = &s_big[wave*CQ*36];
    #pragma unroll 4
    for (int s = 0; s < CQ; ++s) {
      const float* sl = base + s*36;
      float t = sl[32+h] * sl[hp];
      float4 B4 = *(const float4*)&sl[16 + nb*4];
      a0 += t*B4.x; a1 += t*B4.y; a2 += t*B4.z; a3 += t*B4.w;
    }
    *(float4*)(Sc + cg*256 + hp*16 + nb*4) = make_float4(a0,a1,a2,a3);
    if (lane == 0) { Pc[cg*2] = cee0; Pc[cg*2+1] = cee1; }
  } else {
    // ---- y init: D*x + inter-chunk contribution (consumes sv early) ----
    float D0 = Dvec[0], D1 = Dvec[1];
    float y[16];
    #pragma unroll
    for (int hp = 0; hp < 16; ++hp) {
      float a = 0.f;
      #pragma unroll
      for (int n = 0; n < 16; ++n) {
        int idx = hp*16 + n;
        a += Cvr[n] * rl(sv[idx & 3], idx >> 2);
      }
      y[hp] = ((hp < 8) ? D0 : D1)*xv[hp] + ((hp < 8) ? ce0 : ce1)*a;
    }
    // ---- intra-chunk quadratic scan via readlane broadcasts ----
    #pragma unroll 1
    for (int s = 0; s < CQ; ++s) {
      float gg = 0.f;
      #pragma unroll
      for (int n = 0; n < 16; ++n) gg += Cvr[n] * rl(Bv[n], s);
      float wA = ce0 * (rl(cf0, s) * gg);
      float wB = ce1 * (rl(cf1, s) * gg);
      bool ok = (s <= lane);
      wA = ok ? wA : 0.f; wB = ok ? wB : 0.f;
      #pragma unroll
      for (int p = 0; p < 8; ++p) {
        y[p]   += wA * rl(xv[p],   s);
        y[8+p] += wB * rl(xv[8+p], s);
      }
    }
    // ---- gate, RMS norm, out-proj, +u residual ----
    float yv[16]; float ss = 0.f;
    #pragma unroll
    for (int d = 0; d < 16; ++d) {
      float zz = 0.f;
      #pragma unroll
      for (int g = 0; g < 8; ++g) zz += u[g]*w_in[d*8+g];
      float v = y[d] * (zz * sigu(zz));
      yv[d] = v; ss += v*v;
    }
    float scn = rsqrtf(ss*(1.f/16.f) + 1e-5f);
    #pragma unroll
    for (int d = 0; d < 16; ++d) yv[d] *= scn * norm_w[d];
    float og[8];
    #pragma unroll
    for (int g = 0; g < 8; ++g) {
      float a = u[g];
      #pragma unroll
      for (int d = 0; d < 16; ++d) a += yv[d]*w_out[g*16+d];
      og[g] = a;
    }
    float* gp = gf + pos*8;
    *(float4*)gp     = make_float4(og[0],og[1],og[2],og[3]);
    *(float4*)(gp+4) = make_float4(og[4],og[5],og[6],og[7]);
  }
}

__global__ __launch_bounds__(256) void k_scan(
    const float* __restrict__ Sc, const float* __restrict__ Pc,
    float* __restrict__ Stin)
{
  int b = blockIdx.x;
  int tid = threadIdx.x;           // hp*16 + n
  int h = tid >> 7;
  float st = 0.f;
  long base = (long)b * NCH;
  #pragma unroll 8
  for (int c = 0; c < NCH; ++c) {
    Stin[(base + c)*256 + tid] = st;
    st = st * Pc[(base + c)*2 + h] + Sc[(base + c)*256 + tid];
  }
}

__global__ __launch_bounds__(256) void k_detok(
    const float* __restrict__ x, const float* __restrict__ gf,
    const float* __restrict__ w_detok, const float* __restrict__ b_detok,
    float* __restrict__ out)
{
  long idx = (long)blockIdx.x * 256 + threadIdx.x;
  int b = (int)(idx >> 14);
  int l = (int)(idx & (SL-1));
  float gv[8];
  const float* gp = gf + idx*8;
  { float4 a = *(const float4*)gp, c = *(const float4*)(gp+4);
    gv[0]=a.x;gv[1]=a.y;gv[2]=a.z;gv[3]=a.w;gv[4]=c.x;gv[5]=c.y;gv[6]=c.z;gv[7]=c.w; }
  const float* xp = x + (long)b*NC*HW + l;
  float* op = out + (long)b*NC*HW + l;
  #pragma unroll 4
  for (int c = 0; c < NC; ++c) {
    float a = b_detok[c] + xp[(long)c*HW];
    #pragma unroll
    for (int g = 0; g < 8; ++g) a += gv[g]*w_detok[c*8+g];   // uniform -> s_load
    op[(long)c*HW] = a;
  }
}
} // namespace

extern "C" void kernel_launch(void* const* d_in, const int* in_sizes, int n_in,
                              void* d_out, int out_size, void* d_ws, size_t ws_size,
                              hipStream_t stream)
{
  const float* x       = (const float*)d_in[0];
  const float* w_tok   = (const float*)d_in[1];
  const float* b_tok   = (const float*)d_in[2];
  const float* w_detok = (const float*)d_in[3];
  const float* b_detok = (const float*)d_in[4];
  const float* w_in    = (const float*)d_in[5];
  const float* w_conv  = (const float*)d_in[6];
  const float* b_conv  = (const float*)d_in[7];
  const float* dt_bias = (const float*)d_in[8];
  const float* A_log   = (const float*)d_in[9];
  const float* Dvec    = (const float*)d_in[10];
  const float* norm_w  = (const float*)d_in[11];
  const float* w_out   = (const float*)d_in[12];
  float* out = (float*)d_out;

  float* ws   = (float*)d_ws;
  float* g0   = ws;
  float* gf   = g0 + (long)NB*SL*NG;
  float* Sc   = gf + (long)NB*SL*NG;
  float* Pc   = Sc + (long)NB*NCH*256;
  float* Stin = Pc + (long)NB*NCH*2;

  k_tok<<<NB*SL/256, 256, 0, stream>>>(x, w_tok, b_tok, g0);
  k_chunk<0><<<NB*NCH/WCH, 256, 0, stream>>>(g0, w_in, w_conv, b_conv, dt_bias,
                                             A_log, Dvec, norm_w, w_out,
                                             Sc, Pc, nullptr, nullptr);
  k_scan<<<NB, 256, 0, stream>>>(Sc, Pc, Stin);
  k_chunk<1><<<NB*NCH/WCH, 256, 0, stream>>>(g0, w_in, w_conv, b_conv, dt_bias,
                                             A_log, Dvec, norm_w, w_out,
                                             Sc, Pc, Stin, gf);
  k_detok<<<NB*SL/256, 256, 0, stream>>>(x, gf, w_detok, b_detok, out);
}

// Round 5
// 160.545 us; speedup vs baseline: 1.0174x; 1.0174x over previous
//
#include <hip/hip_runtime.h>

namespace {
constexpr int NB   = 16;
constexpr int NC   = 64;
constexpr int HW   = 128*128;
constexpr int SL   = 16384;
constexpr int NG   = 8;
constexpr int CQ   = 64;
constexpr int NCH  = SL/CQ;   // 256
constexpr int WCH  = 4;       // chunks (waves) per block

__device__ __forceinline__ float frcp(float x){ return __builtin_amdgcn_rcpf(x); }
__device__ __forceinline__ float rl(float v, int s){
  return __int_as_float(__builtin_amdgcn_readlane(__float_as_int(v), s));
}
__device__ __forceinline__ float sigu(float a){ return frcp(1.0f + __expf(-a)); }

__global__ __launch_bounds__(256) void k_tok(
    const float* __restrict__ x, const float* __restrict__ w_tok,
    const float* __restrict__ b_tok, float* __restrict__ g0)
{
  long idx = (long)blockIdx.x * 256 + threadIdx.x;
  int b = (int)(idx >> 14);
  int l = (int)(idx & (SL-1));
  float acc[8];
  #pragma unroll
  for (int g = 0; g < 8; ++g) acc[g] = b_tok[g];
  const float* xp = x + (long)b*NC*HW + l;
  #pragma unroll 8
  for (int c = 0; c < NC; ++c) {
    float v = xp[(long)c*HW];
    #pragma unroll
    for (int g = 0; g < 8; ++g) acc[g] += v * w_tok[g*NC + c];   // uniform -> s_load
  }
  float* gp = g0 + idx*8;
  *(float4*)gp     = make_float4(acc[0],acc[1],acc[2],acc[3]);
  *(float4*)(gp+4) = make_float4(acc[4],acc[5],acc[6],acc[7]);
}

// PASS 0: per-chunk state contribution Sc + decay Pc.  PASS 1: outputs -> gf.
// NOTE: no occupancy attribute — forced 64-VGPR allocation spilled ~55MB/dispatch
// (rounds 3/4). Default allocator does not spill; live set ~100 regs -> 4 waves/EU.
template<int PASS>
__global__ __launch_bounds__(256)
void k_chunk(
    const float* __restrict__ g0, const float* __restrict__ w_in,
    const float* __restrict__ w_conv, const float* __restrict__ b_conv,
    const float* __restrict__ dt_bias, const float* __restrict__ A_log,
    const float* __restrict__ Dvec, const float* __restrict__ norm_w,
    const float* __restrict__ w_out,
    float* __restrict__ Sc, float* __restrict__ Pc,
    const float* __restrict__ Stin, float* __restrict__ gf)
{
  constexpr int JMAX = (PASS==1) ? 48 : 32;      // PASS0 needs x,B only
  __shared__ float s_big[(PASS==0) ? WCH*CQ*36 : 1];

  int tid = threadIdx.x, lane = tid & 63, wave = tid >> 6;
  int b   = blockIdx.x >> 6;
  int chB = (blockIdx.x & 63)*WCH + wave;
  long cg = (long)b*NCH + chB;
  int l0  = chB*CQ;
  long pos = (long)b*SL + l0 + lane;

  // own u (coalesced)
  float u[8];
  { const float* up = g0 + pos*8;
    float4 a = *(const float4*)up, c = *(const float4*)(up+4);
    u[0]=a.x;u[1]=a.y;u[2]=a.z;u[3]=a.w;u[4]=c.x;u[5]=c.y;u[6]=c.z;u[7]=c.w; }

  // ---- halo pre-values in registers (no LDS, no barrier) ----
  // hA: lane = p*32 + j   (p in {0,1} = pos l0-2+p, j in 0..31)
  // hB: lane = p*16 + (j-32)  for j in 32..47 (PASS1 only; lanes 0..31)
  float hA = 0.f, hB = 0.f;
  {
    int pA = lane >> 5, jA = lane & 31;
    int hlA = l0 - 2 + pA;
    float uA[8] = {0,0,0,0,0,0,0,0};
    if (hlA >= 0) {
      const float* hp2 = g0 + ((long)b*SL + hlA)*8;
      float4 a = *(const float4*)hp2, c = *(const float4*)(hp2+4);
      uA[0]=a.x;uA[1]=a.y;uA[2]=a.z;uA[3]=a.w;uA[4]=c.x;uA[5]=c.y;uA[6]=c.z;uA[7]=c.w;
    }
    #pragma unroll
    for (int g = 0; g < 8; ++g) hA += uA[g]*w_in[(16+jA)*8+g];
    if constexpr (PASS==1) {
      int pB = (lane >> 4) & 1, jB = 32 + (lane & 15);
      int hlB = l0 - 2 + pB;
      float uB[8] = {0,0,0,0,0,0,0,0};
      if (hlB >= 0) {
        const float* hp2 = g0 + ((long)b*SL + hlB)*8;
        float4 a = *(const float4*)hp2, c = *(const float4*)(hp2+4);
        uB[0]=a.x;uB[1]=a.y;uB[2]=a.z;uB[3]=a.w;uB[4]=c.x;uB[5]=c.y;uB[6]=c.z;uB[7]=c.w;
      }
      #pragma unroll
      for (int g = 0; g < 8; ++g) hB += uB[g]*w_in[(16+jB)*8+g];
    }
  }

  // ---- blocked in-proj + causal conv + silu (weights via s_load) ----
  float xv[16], Bv[16];
  float Cvr[(PASS==1) ? 16 : 1];
  #pragma unroll
  for (int jb = 0; jb < JMAX/8; ++jb) {
    float pr[8];
    #pragma unroll
    for (int jj = 0; jj < 8; ++jj) {
      int j = jb*8 + jj;
      float a = 0.f;
      #pragma unroll
      for (int g = 0; g < 8; ++g) a += u[g]*w_in[(16+j)*8+g];   // uniform -> s_load
      pr[jj] = a;
    }
    #pragma unroll
    for (int jj = 0; jj < 8; ++jj) {
      int j = jb*8 + jj;
      float pm1 = __shfl_up(pr[jj], 1);
      float pm2 = __shfl_up(pr[jj], 2);
      float h0j = (j < 32) ? rl(hA, j)      : rl(hB, j-32);
      float h1j = (j < 32) ? rl(hA, 32+j)   : rl(hB, 16+(j-32));
      pm1 = (lane == 0) ? h1j : pm1;
      pm2 = (lane == 0) ? h0j : ((lane == 1) ? h1j : pm2);
      float a = b_conv[j] + pm2*w_conv[j*3] + pm1*w_conv[j*3+1] + pr[jj]*w_conv[j*3+2];
      float s = a * sigu(a);
      if (j < 16) xv[j] = s;
      else if (j < 32) Bv[j-16] = s;
      else { if constexpr (PASS==1) Cvr[j-32] = s; }
    }
  }

  // ---- dt (softplus) + cumsum of A*dt via shuffle prefix ----
  float dt0, dt1;
  { float a = dt_bias[0];
    #pragma unroll
    for (int g = 0; g < 8; ++g) a += u[g]*w_in[64*8+g];
    dt0 = (a > 20.f) ? a : log1pf(__expf(a));
    float b2 = dt_bias[1];
    #pragma unroll
    for (int g = 0; g < 8; ++g) b2 += u[g]*w_in[65*8+g];
    dt1 = (b2 > 20.f) ? b2 : log1pf(__expf(b2)); }
  float A0 = -__expf(A_log[0]), A1 = -__expf(A_log[1]);
  float c0 = A0*dt0, c1 = A1*dt1;
  #pragma unroll
  for (int off = 1; off < 64; off <<= 1) {
    float t0 = __shfl_up(c0, off), t1 = __shfl_up(c1, off);
    if (lane >= off) { c0 += t0; c1 += t1; }
  }
  float ce0 = __expf(c0), ce1 = __expf(c1);
  float cf0 = __expf(-c0)*dt0, cf1 = __expf(-c1)*dt1;
  float cee0 = rl(ce0, 63), cee1 = rl(ce1, 63);

  if constexpr (PASS==0) {
    float* slab = &s_big[wave*CQ*36 + lane*36];
    #pragma unroll
    for (int k = 0; k < 16; ++k) { slab[k] = xv[k]; slab[16+k] = Bv[k]; }
    slab[32] = cee0*cf0; slab[33] = cee1*cf1;
    __builtin_amdgcn_wave_barrier();
    int hp = lane >> 2, nb = lane & 3, h = hp >> 3;
    float a0=0.f, a1=0.f, a2=0.f, a3=0.f;
    const float* base = &s_big[wave*CQ*36];
    #pragma unroll 4
    for (int s = 0; s < CQ; ++s) {
      const float* sl = base + s*36;
      float t = sl[32+h] * sl[hp];
      float4 B4 = *(const float4*)&sl[16 + nb*4];
      a0 += t*B4.x; a1 += t*B4.y; a2 += t*B4.z; a3 += t*B4.w;
    }
    *(float4*)(Sc + cg*256 + hp*16 + nb*4) = make_float4(a0,a1,a2,a3);
    if (lane == 0) { Pc[cg*2] = cee0; Pc[cg*2+1] = cee1; }
  } else {
    // ---- y init: D*x + inter-chunk contribution (state loaded here) ----
    float sv[4];
    { float4 t = *(const float4*)(Stin + cg*256 + lane*4);
      sv[0]=t.x; sv[1]=t.y; sv[2]=t.z; sv[3]=t.w; }
    float D0 = Dvec[0], D1 = Dvec[1];
    float y[16];
    #pragma unroll
    for (int hp = 0; hp < 16; ++hp) {
      float a = 0.f;
      #pragma unroll
      for (int n = 0; n < 16; ++n) {
        int idx = hp*16 + n;
        a += Cvr[n] * rl(sv[idx & 3], idx >> 2);
      }
      y[hp] = ((hp < 8) ? D0 : D1)*xv[hp] + ((hp < 8) ? ce0 : ce1)*a;
    }
    // ---- intra-chunk quadratic scan via readlane broadcasts ----
    // (u is dead here; reloaded at epilogue to cut hot-loop pressure)
    #pragma unroll 1
    for (int s = 0; s < CQ; ++s) {
      float gg = 0.f;
      #pragma unroll
      for (int n = 0; n < 16; ++n) gg += Cvr[n] * rl(Bv[n], s);
      float wA = ce0 * (rl(cf0, s) * gg);
      float wB = ce1 * (rl(cf1, s) * gg);
      bool ok = (s <= lane);
      wA = ok ? wA : 0.f; wB = ok ? wB : 0.f;
      #pragma unroll
      for (int p = 0; p < 8; ++p) {
        y[p]   += wA * rl(xv[p],   s);
        y[8+p] += wB * rl(xv[8+p], s);
      }
    }
    // ---- epilogue: reload u, gate, RMS norm, out-proj, +u residual ----
    float ur[8];
    { const float* up = g0 + pos*8;
      float4 a = *(const float4*)up, c = *(const float4*)(up+4);
      ur[0]=a.x;ur[1]=a.y;ur[2]=a.z;ur[3]=a.w;ur[4]=c.x;ur[5]=c.y;ur[6]=c.z;ur[7]=c.w; }
    float yv[16]; float ss = 0.f;
    #pragma unroll
    for (int d = 0; d < 16; ++d) {
      float zz = 0.f;
      #pragma unroll
      for (int g = 0; g < 8; ++g) zz += ur[g]*w_in[d*8+g];
      float v = y[d] * (zz * sigu(zz));
      yv[d] = v; ss += v*v;
    }
    float scn = rsqrtf(ss*(1.f/16.f) + 1e-5f);
    #pragma unroll
    for (int d = 0; d < 16; ++d) yv[d] *= scn * norm_w[d];
    float og[8];
    #pragma unroll
    for (int g = 0; g < 8; ++g) {
      float a = ur[g];
      #pragma unroll
      for (int d = 0; d < 16; ++d) a += yv[d]*w_out[g*16+d];
      og[g] = a;
    }
    float* gp = gf + pos*8;
    *(float4*)gp     = make_float4(og[0],og[1],og[2],og[3]);
    *(float4*)(gp+4) = make_float4(og[4],og[5],og[6],og[7]);
  }
}

__global__ __launch_bounds__(256) void k_scan(
    const float* __restrict__ Sc, const float* __restrict__ Pc,
    float* __restrict__ Stin)
{
  int b = blockIdx.x;
  int tid = threadIdx.x;           // hp*16 + n
  int h = tid >> 7;
  float st = 0.f;
  long base = (long)b * NCH;
  #pragma unroll 8
  for (int c = 0; c < NCH; ++c) {
    Stin[(base + c)*256 + tid] = st;
    st = st * Pc[(base + c)*2 + h] + Sc[(base + c)*256 + tid];
  }
}

__global__ __launch_bounds__(256) void k_detok(
    const float* __restrict__ x, const float* __restrict__ gf,
    const float* __restrict__ w_detok, const float* __restrict__ b_detok,
    float* __restrict__ out)
{
  long idx = (long)blockIdx.x * 256 + threadIdx.x;
  int b = (int)(idx >> 14);
  int l = (int)(idx & (SL-1));
  float gv[8];
  const float* gp = gf + idx*8;
  { float4 a = *(const float4*)gp, c = *(const float4*)(gp+4);
    gv[0]=a.x;gv[1]=a.y;gv[2]=a.z;gv[3]=a.w;gv[4]=c.x;gv[5]=c.y;gv[6]=c.z;gv[7]=c.w; }
  const float* xp = x + (long)b*NC*HW + l;
  float* op = out + (long)b*NC*HW + l;
  #pragma unroll 4
  for (int c = 0; c < NC; ++c) {
    float a = b_detok[c] + xp[(long)c*HW];
    #pragma unroll
    for (int g = 0; g < 8; ++g) a += gv[g]*w_detok[c*8+g];   // uniform -> s_load
    op[(long)c*HW] = a;
  }
}
} // namespace

extern "C" void kernel_launch(void* const* d_in, const int* in_sizes, int n_in,
                              void* d_out, int out_size, void* d_ws, size_t ws_size,
                              hipStream_t stream)
{
  const float* x       = (const float*)d_in[0];
  const float* w_tok   = (const float*)d_in[1];
  const float* b_tok   = (const float*)d_in[2];
  const float* w_detok = (const float*)d_in[3];
  const float* b_detok = (const float*)d_in[4];
  const float* w_in    = (const float*)d_in[5];
  const float* w_conv  = (const float*)d_in[6];
  const float* b_conv  = (const float*)d_in[7];
  const float* dt_bias = (const float*)d_in[8];
  const float* A_log   = (const float*)d_in[9];
  const float* Dvec    = (const float*)d_in[10];
  const float* norm_w  = (const float*)d_in[11];
  const float* w_out   = (const float*)d_in[12];
  float* out = (float*)d_out;

  float* ws   = (float*)d_ws;
  float* g0   = ws;
  float* gf   = g0 + (long)NB*SL*NG;
  float* Sc   = gf + (long)NB*SL*NG;
  float* Pc   = Sc + (long)NB*NCH*256;
  float* Stin = Pc + (long)NB*NCH*2;

  k_tok<<<NB*SL/256, 256, 0, stream>>>(x, w_tok, b_tok, g0);
  k_chunk<0><<<NB*NCH/WCH, 256, 0, stream>>>(g0, w_in, w_conv, b_conv, dt_bias,
                                             A_log, Dvec, norm_w, w_out,
                                             Sc, Pc, nullptr, nullptr);
  k_scan<<<NB, 256, 0, stream>>>(Sc, Pc, Stin);
  k_chunk<1><<<NB*NCH/WCH, 256, 0, stream>>>(g0, w_in, w_conv, b_conv, dt_bias,
                                             A_log, Dvec, norm_w, w_out,
                                             Sc, Pc, Stin, gf);
  k_detok<<<NB*SL/256, 256, 0, stream>>>(x, gf, w_detok, b_detok, out);
}

// Round 6
// 147.364 us; speedup vs baseline: 1.1084x; 1.0894x over previous
//
#include <hip/hip_runtime.h>

namespace {
constexpr int NB   = 16;
constexpr int NC   = 64;
constexpr int HW   = 128*128;
constexpr int SL   = 16384;
constexpr int NG   = 8;
constexpr int CQ   = 64;
constexpr int NCH  = SL/CQ;   // 256
constexpr int WCH  = 4;       // chunks (waves) per block

__device__ __forceinline__ float frcp(float x){ return __builtin_amdgcn_rcpf(x); }
__device__ __forceinline__ float rl(float v, int s){
  return __int_as_float(__builtin_amdgcn_readlane(__float_as_int(v), s));
}
__device__ __forceinline__ float sigu(float a){ return frcp(1.0f + __expf(-a)); }
// branchless softplus: max(a,0) + log(1+exp(-|a|))
__device__ __forceinline__ float softplusf(float a){
  float e = __expf(-fabsf(a));
  return fmaxf(a, 0.f) + __logf(1.f + e);
}

__global__ __launch_bounds__(256) void k_tok(
    const float* __restrict__ x, const float* __restrict__ w_tok,
    const float* __restrict__ b_tok, float* __restrict__ g0)
{
  __shared__ float s_wt[NC][8];   // [c][g] (transposed stage)
  __shared__ float s_bt[8];
  for (int i = threadIdx.x; i < NC*8; i += 256) s_wt[i>>3][i&7] = w_tok[(i&7)*NC + (i>>3)];
  if (threadIdx.x < 8) s_bt[threadIdx.x] = b_tok[threadIdx.x];
  __syncthreads();
  long idx = (long)blockIdx.x * 256 + threadIdx.x;
  int b = (int)(idx >> 14);
  int l = (int)(idx & (SL-1));
  float acc[8];
  #pragma unroll
  for (int g = 0; g < 8; ++g) acc[g] = s_bt[g];
  const float* xp = x + (long)b*NC*HW + l;
  #pragma unroll 8
  for (int c = 0; c < NC; ++c) {
    float v = xp[(long)c*HW];
    const float4* wr = (const float4*)s_wt[c];
    float4 w0 = wr[0], w1 = wr[1];
    acc[0] += v*w0.x; acc[1] += v*w0.y; acc[2] += v*w0.z; acc[3] += v*w0.w;
    acc[4] += v*w1.x; acc[5] += v*w1.y; acc[6] += v*w1.z; acc[7] += v*w1.w;
  }
  float* gp = g0 + idx*8;
  *(float4*)gp     = make_float4(acc[0],acc[1],acc[2],acc[3]);
  *(float4*)(gp+4) = make_float4(acc[4],acc[5],acc[6],acc[7]);
}

// PASS 0: per-chunk state contribution Sc + decay Pc.  PASS 1: outputs -> gf.
template<int PASS>
__global__ __launch_bounds__(256)
void k_chunk(
    const float* __restrict__ g0, const float* __restrict__ w_in,
    const float* __restrict__ w_conv, const float* __restrict__ b_conv,
    const float* __restrict__ dt_bias, const float* __restrict__ A_log,
    const float* __restrict__ Dvec, const float* __restrict__ norm_w,
    const float* __restrict__ w_out,
    float* __restrict__ Sc, float* __restrict__ Pc,
    const float* __restrict__ Stin, float* __restrict__ gf)
{
  constexpr int JMAX = (PASS==1) ? 48 : 32;      // PASS0 needs x,B only
  __shared__ float s_win[66][8];                 // in-proj rows (z,xBC,dt)
  __shared__ float s_wc[48][4];                  // w0,w1,w2,bias per conv ch
  __shared__ float s_wout[8][16];
  __shared__ float s_nw[16];
  __shared__ float s_misc[8];                    // A0,A1,dtb0,dtb1,D0,D1
  __shared__ float s_big[(PASS==0) ? WCH*CQ*36 : 1];

  int tid = threadIdx.x, lane = tid & 63, wave = tid >> 6;

  for (int i = tid; i < 66*8; i += 256) s_win[i>>3][i&7] = w_in[i];
  if (tid < 48) {
    s_wc[tid][0] = w_conv[tid*3];   s_wc[tid][1] = w_conv[tid*3+1];
    s_wc[tid][2] = w_conv[tid*3+2]; s_wc[tid][3] = b_conv[tid];
  }
  if (tid < 128) s_wout[tid>>4][tid&15] = w_out[tid];
  if (tid < 16)  s_nw[tid] = norm_w[tid];
  if (tid < 2) {
    s_misc[tid]   = -__expf(A_log[tid]);
    s_misc[2+tid] = dt_bias[tid];
    s_misc[4+tid] = Dvec[tid];
  }
  __syncthreads();

  auto dot8 = [&](const float* uu, int row) -> float {
    const float4* wr = (const float4*)s_win[row];
    float4 w0 = wr[0], w1 = wr[1];
    return uu[0]*w0.x + uu[1]*w0.y + uu[2]*w0.z + uu[3]*w0.w
         + uu[4]*w1.x + uu[5]*w1.y + uu[6]*w1.z + uu[7]*w1.w;
  };

  int b   = blockIdx.x >> 6;                  // NCH/WCH = 64 blocks/batch
  int chB = (blockIdx.x & 63)*WCH + wave;
  long cg = (long)b*NCH + chB;
  int l0  = chB*CQ;
  long pos = (long)b*SL + l0 + lane;

  // own u (coalesced)
  float u[8];
  { const float* up = g0 + pos*8;
    float4 a = *(const float4*)up, c = *(const float4*)(up+4);
    u[0]=a.x;u[1]=a.y;u[2]=a.z;u[3]=a.w;u[4]=c.x;u[5]=c.y;u[6]=c.z;u[7]=c.w; }

  // ---- halo pre-values in registers (clamped unguarded load + select) ----
  // hA: lane = p*32 + j (p in {0,1} = pos l0-2+p, j 0..31)
  // hB: lane = p*16 + (j-32) for j 32..47 (PASS1 only)
  float hA, hB = 0.f;
  {
    int pA = lane >> 5, jA = lane & 31;
    int hlA = l0 - 2 + pA;
    bool okA = (hlA >= 0);
    const float* hp2 = g0 + ((long)b*SL + (okA ? hlA : 0))*8;
    float4 a = *(const float4*)hp2, c = *(const float4*)(hp2+4);
    float uA[8] = {a.x,a.y,a.z,a.w,c.x,c.y,c.z,c.w};
    hA = okA ? dot8(uA, 16+jA) : 0.f;
    if constexpr (PASS==1) {
      int pB = (lane >> 4) & 1, jB = 32 + (lane & 15);
      int hlB = l0 - 2 + pB;
      bool okB = (hlB >= 0);
      const float* hq = g0 + ((long)b*SL + (okB ? hlB : 0))*8;
      float4 a2 = *(const float4*)hq, c2 = *(const float4*)(hq+4);
      float uB[8] = {a2.x,a2.y,a2.z,a2.w,c2.x,c2.y,c2.z,c2.w};
      hB = okB ? dot8(uB, 16+jB) : 0.f;
    }
  }

  // ---- blocked in-proj + causal conv + silu (weights via LDS b128) ----
  float xv[16], Bv[16];
  float Cvr[(PASS==1) ? 16 : 1];
  #pragma unroll
  for (int jb = 0; jb < JMAX/8; ++jb) {
    float pr[8];
    #pragma unroll
    for (int jj = 0; jj < 8; ++jj) pr[jj] = dot8(u, 16 + jb*8 + jj);
    #pragma unroll
    for (int jj = 0; jj < 8; ++jj) {
      int j = jb*8 + jj;
      float pm1 = __shfl_up(pr[jj], 1);
      float pm2 = __shfl_up(pr[jj], 2);
      float h0j = (j < 32) ? rl(hA, j)      : rl(hB, j-32);
      float h1j = (j < 32) ? rl(hA, 32+j)   : rl(hB, 16+(j-32));
      pm1 = (lane == 0) ? h1j : pm1;
      pm2 = (lane == 0) ? h0j : ((lane == 1) ? h1j : pm2);
      float4 wc = *(const float4*)s_wc[j];
      float a = wc.w + pm2*wc.x + pm1*wc.y + pr[jj]*wc.z;
      float s = a * sigu(a);
      if (j < 16) xv[j] = s;
      else if (j < 32) Bv[j-16] = s;
      else { if constexpr (PASS==1) Cvr[j-32] = s; }
    }
  }

  // ---- dt (softplus) + cumsum of A*dt via shuffle prefix ----
  float dt0 = softplusf(dot8(u, 64) + s_misc[2]);
  float dt1 = softplusf(dot8(u, 65) + s_misc[3]);
  float c0 = s_misc[0]*dt0, c1 = s_misc[1]*dt1;
  #pragma unroll
  for (int off = 1; off < 64; off <<= 1) {
    float t0 = __shfl_up(c0, off), t1 = __shfl_up(c1, off);
    if (lane >= off) { c0 += t0; c1 += t1; }
  }
  float ce0 = __expf(c0), ce1 = __expf(c1);
  float cf0 = __expf(-c0)*dt0, cf1 = __expf(-c1)*dt1;
  float cee0 = rl(ce0, 63), cee1 = rl(ce1, 63);

  if constexpr (PASS==0) {
    float* slab = &s_big[wave*CQ*36 + lane*36];
    #pragma unroll
    for (int k = 0; k < 16; ++k) { slab[k] = xv[k]; slab[16+k] = Bv[k]; }
    slab[32] = cee0*cf0; slab[33] = cee1*cf1;
    __builtin_amdgcn_wave_barrier();
    int hp = lane >> 2, nb = lane & 3, h = hp >> 3;
    float a0=0.f, a1=0.f, a2=0.f, a3=0.f;
    const float* base = &s_big[wave*CQ*36];
    #pragma unroll 4
    for (int s = 0; s < CQ; ++s) {
      const float* sl = base + s*36;
      float t = sl[32+h] * sl[hp];
      float4 B4 = *(const float4*)&sl[16 + nb*4];
      a0 += t*B4.x; a1 += t*B4.y; a2 += t*B4.z; a3 += t*B4.w;
    }
    *(float4*)(Sc + cg*256 + hp*16 + nb*4) = make_float4(a0,a1,a2,a3);
    if (lane == 0) { Pc[cg*2] = cee0; Pc[cg*2+1] = cee1; }
  } else {
    // ---- y init: D*x + inter-chunk contribution ----
    float sv[4];
    { float4 t = *(const float4*)(Stin + cg*256 + lane*4);
      sv[0]=t.x; sv[1]=t.y; sv[2]=t.z; sv[3]=t.w; }
    float D0 = s_misc[4], D1 = s_misc[5];
    float y[16];
    #pragma unroll
    for (int hp = 0; hp < 16; ++hp) {
      float a = 0.f;
      #pragma unroll
      for (int n = 0; n < 16; ++n) {
        int idx = hp*16 + n;
        a += Cvr[n] * rl(sv[idx & 3], idx >> 2);
      }
      y[hp] = ((hp < 8) ? D0 : D1)*xv[hp] + ((hp < 8) ? ce0 : ce1)*a;
    }
    // ---- intra-chunk quadratic scan (tree-reduced gg, unroll x2) ----
    auto body = [&](int s) {
      float p0  = Cvr[0] *rl(Bv[0], s), p1  = Cvr[1] *rl(Bv[1], s);
      float p2  = Cvr[2] *rl(Bv[2], s), p3  = Cvr[3] *rl(Bv[3], s);
      float p4  = Cvr[4] *rl(Bv[4], s), p5  = Cvr[5] *rl(Bv[5], s);
      float p6  = Cvr[6] *rl(Bv[6], s), p7  = Cvr[7] *rl(Bv[7], s);
      float p8  = Cvr[8] *rl(Bv[8], s), p9  = Cvr[9] *rl(Bv[9], s);
      float p10 = Cvr[10]*rl(Bv[10],s), p11 = Cvr[11]*rl(Bv[11],s);
      float p12 = Cvr[12]*rl(Bv[12],s), p13 = Cvr[13]*rl(Bv[13],s);
      float p14 = Cvr[14]*rl(Bv[14],s), p15 = Cvr[15]*rl(Bv[15],s);
      float q0 = p0+p1, q1 = p2+p3, q2 = p4+p5, q3 = p6+p7;
      float q4 = p8+p9, q5 = p10+p11, q6 = p12+p13, q7 = p14+p15;
      float gg = ((q0+q1)+(q2+q3)) + ((q4+q5)+(q6+q7));
      float wA = ce0 * (rl(cf0, s) * gg);
      float wB = ce1 * (rl(cf1, s) * gg);
      bool ok = (s <= lane);
      wA = ok ? wA : 0.f; wB = ok ? wB : 0.f;
      #pragma unroll
      for (int p = 0; p < 8; ++p) {
        y[p]   += wA * rl(xv[p],   s);
        y[8+p] += wB * rl(xv[8+p], s);
      }
    };
    #pragma unroll 1
    for (int s = 0; s < CQ; s += 2) { body(s); body(s+1); }

    // ---- gate, RMS norm, out-proj, +u residual ----
    float yv[16]; float ss = 0.f;
    #pragma unroll
    for (int d = 0; d < 16; ++d) {
      float zz = dot8(u, d);
      float v = y[d] * (zz * sigu(zz));
      yv[d] = v; ss += v*v;
    }
    float scn = rsqrtf(ss*(1.f/16.f) + 1e-5f);
    { const float4* nw = (const float4*)s_nw;
      float4 n0 = nw[0], n1 = nw[1], n2 = nw[2], n3 = nw[3];
      yv[0]*=scn*n0.x; yv[1]*=scn*n0.y; yv[2]*=scn*n0.z; yv[3]*=scn*n0.w;
      yv[4]*=scn*n1.x; yv[5]*=scn*n1.y; yv[6]*=scn*n1.z; yv[7]*=scn*n1.w;
      yv[8]*=scn*n2.x; yv[9]*=scn*n2.y; yv[10]*=scn*n2.z; yv[11]*=scn*n2.w;
      yv[12]*=scn*n3.x; yv[13]*=scn*n3.y; yv[14]*=scn*n3.z; yv[15]*=scn*n3.w; }
    float og[8];
    #pragma unroll
    for (int g = 0; g < 8; ++g) {
      const float4* wr = (const float4*)s_wout[g];
      float4 w0 = wr[0], w1 = wr[1], w2 = wr[2], w3 = wr[3];
      float a = u[g];
      a += yv[0]*w0.x + yv[1]*w0.y + yv[2]*w0.z + yv[3]*w0.w;
      a += yv[4]*w1.x + yv[5]*w1.y + yv[6]*w1.z + yv[7]*w1.w;
      a += yv[8]*w2.x + yv[9]*w2.y + yv[10]*w2.z + yv[11]*w2.w;
      a += yv[12]*w3.x + yv[13]*w3.y + yv[14]*w3.z + yv[15]*w3.w;
      og[g] = a;
    }
    float* gp = gf + pos*8;
    *(float4*)gp     = make_float4(og[0],og[1],og[2],og[3]);
    *(float4*)(gp+4) = make_float4(og[4],og[5],og[6],og[7]);
  }
}

__global__ __launch_bounds__(256) void k_scan(
    const float* __restrict__ Sc, const float* __restrict__ Pc,
    float* __restrict__ Stin)
{
  int b = blockIdx.x;
  int tid = threadIdx.x;           // hp*16 + n
  int h = tid >> 7;
  float st = 0.f;
  long base = (long)b * NCH;
  #pragma unroll 8
  for (int c = 0; c < NCH; ++c) {
    Stin[(base + c)*256 + tid] = st;
    st = st * Pc[(base + c)*2 + h] + Sc[(base + c)*256 + tid];
  }
}

__global__ __launch_bounds__(256) void k_detok(
    const float* __restrict__ x, const float* __restrict__ gf,
    const float* __restrict__ w_detok, const float* __restrict__ b_detok,
    float* __restrict__ out)
{
  __shared__ float s_wd[NC][8];
  __shared__ float s_bd[NC];
  for (int i = threadIdx.x; i < NC*8; i += 256) s_wd[i>>3][i&7] = w_detok[i];
  if (threadIdx.x < NC) s_bd[threadIdx.x] = b_detok[threadIdx.x];
  __syncthreads();
  long idx = (long)blockIdx.x * 256 + threadIdx.x;
  int b = (int)(idx >> 14);
  int l = (int)(idx & (SL-1));
  float gv[8];
  const float* gp = gf + idx*8;
  { float4 a = *(const float4*)gp, c = *(const float4*)(gp+4);
    gv[0]=a.x;gv[1]=a.y;gv[2]=a.z;gv[3]=a.w;gv[4]=c.x;gv[5]=c.y;gv[6]=c.z;gv[7]=c.w; }
  const float* xp = x + (long)b*NC*HW + l;
  float* op = out + (long)b*NC*HW + l;
  #pragma unroll 4
  for (int c = 0; c < NC; ++c) {
    const float4* wr = (const float4*)s_wd[c];
    float4 w0 = wr[0], w1 = wr[1];
    float a = s_bd[c] + xp[(long)c*HW];
    a += gv[0]*w0.x + gv[1]*w0.y + gv[2]*w0.z + gv[3]*w0.w;
    a += gv[4]*w1.x + gv[5]*w1.y + gv[6]*w1.z + gv[7]*w1.w;
    op[(long)c*HW] = a;
  }
}
} // namespace

extern "C" void kernel_launch(void* const* d_in, const int* in_sizes, int n_in,
                              void* d_out, int out_size, void* d_ws, size_t ws_size,
                              hipStream_t stream)
{
  const float* x       = (const float*)d_in[0];
  const float* w_tok   = (const float*)d_in[1];
  const float* b_tok   = (const float*)d_in[2];
  const float* w_detok = (const float*)d_in[3];
  const float* b_detok = (const float*)d_in[4];
  const float* w_in    = (const float*)d_in[5];
  const float* w_conv  = (const float*)d_in[6];
  const float* b_conv  = (const float*)d_in[7];
  const float* dt_bias = (const float*)d_in[8];
  const float* A_log   = (const float*)d_in[9];
  const float* Dvec    = (const float*)d_in[10];
  const float* norm_w  = (const float*)d_in[11];
  const float* w_out   = (const float*)d_in[12];
  float* out = (float*)d_out;

  float* ws   = (float*)d_ws;
  float* g0   = ws;
  float* gf   = g0 + (long)NB*SL*NG;
  float* Sc   = gf + (long)NB*SL*NG;
  float* Pc   = Sc + (long)NB*NCH*256;
  float* Stin = Pc + (long)NB*NCH*2;

  k_tok<<<NB*SL/256, 256, 0, stream>>>(x, w_tok, b_tok, g0);
  k_chunk<0><<<NB*NCH/WCH, 256, 0, stream>>>(g0, w_in, w_conv, b_conv, dt_bias,
                                             A_log, Dvec, norm_w, w_out,
                                             Sc, Pc, nullptr, nullptr);
  k_scan<<<NB, 256, 0, stream>>>(Sc, Pc, Stin);
  k_chunk<1><<<NB*NCH/WCH, 256, 0, stream>>>(g0, w_in, w_conv, b_conv, dt_bias,
                                             A_log, Dvec, norm_w, w_out,
                                             Sc, Pc, Stin, gf);
  k_detok<<<NB*SL/256, 256, 0, stream>>>(x, gf, w_detok, b_detok, out);
}

// Round 7
// 129.801 us; speedup vs baseline: 1.2584x; 1.1353x over previous
//
#include <hip/hip_runtime.h>

namespace {
constexpr int NB   = 16;
constexpr int NC   = 64;
constexpr int HW   = 128*128;
constexpr int SL   = 16384;
constexpr int NG   = 8;
constexpr int CQ   = 64;
constexpr int NCH  = SL/CQ;   // 256
constexpr int WCH  = 4;       // chunks (waves) per block
constexpr int SLABF = 2176;   // floats per wave: X 1024 | B 1024 | CF 128

typedef float v2f __attribute__((__ext_vector_type__(2)));

__device__ __forceinline__ float frcp(float x){ return __builtin_amdgcn_rcpf(x); }
__device__ __forceinline__ float rl(float v, int s){
  return __int_as_float(__builtin_amdgcn_readlane(__float_as_int(v), s));
}
__device__ __forceinline__ float sigu(float a){ return frcp(1.0f + __expf(-a)); }
__device__ __forceinline__ float softplusf(float a){
  float e = __expf(-fabsf(a));
  return fmaxf(a, 0.f) + __logf(1.f + e);
}
__device__ __forceinline__ v2f mkv2(float a, float b){ v2f r; r.x=a; r.y=b; return r; }

__global__ __launch_bounds__(256) void k_tok(
    const float* __restrict__ x, const float* __restrict__ w_tok,
    const float* __restrict__ b_tok, float* __restrict__ g0)
{
  __shared__ float s_wt[NC][8];
  __shared__ float s_bt[8];
  for (int i = threadIdx.x; i < NC*8; i += 256) s_wt[i>>3][i&7] = w_tok[(i&7)*NC + (i>>3)];
  if (threadIdx.x < 8) s_bt[threadIdx.x] = b_tok[threadIdx.x];
  __syncthreads();
  long idx = (long)blockIdx.x * 256 + threadIdx.x;
  int b = (int)(idx >> 14);
  int l = (int)(idx & (SL-1));
  float acc[8];
  #pragma unroll
  for (int g = 0; g < 8; ++g) acc[g] = s_bt[g];
  const float* xp = x + (long)b*NC*HW + l;
  #pragma unroll 8
  for (int c = 0; c < NC; ++c) {
    float v = xp[(long)c*HW];
    const float4* wr = (const float4*)s_wt[c];
    float4 w0 = wr[0], w1 = wr[1];
    acc[0] += v*w0.x; acc[1] += v*w0.y; acc[2] += v*w0.z; acc[3] += v*w0.w;
    acc[4] += v*w1.x; acc[5] += v*w1.y; acc[6] += v*w1.z; acc[7] += v*w1.w;
  }
  float* gp = g0 + idx*8;
  *(float4*)gp     = make_float4(acc[0],acc[1],acc[2],acc[3]);
  *(float4*)(gp+4) = make_float4(acc[4],acc[5],acc[6],acc[7]);
}

// PASS 0: per-chunk state contribution Sc + decay Pc.  PASS 1: outputs -> gf.
template<int PASS>
__global__ __launch_bounds__(256)
void k_chunk(
    const float* __restrict__ g0, const float* __restrict__ w_in,
    const float* __restrict__ w_conv, const float* __restrict__ b_conv,
    const float* __restrict__ dt_bias, const float* __restrict__ A_log,
    const float* __restrict__ Dvec, const float* __restrict__ norm_w,
    const float* __restrict__ w_out,
    float* __restrict__ Sc, float* __restrict__ Pc,
    const float* __restrict__ Stin, float* __restrict__ gf)
{
  constexpr int JMAX = (PASS==1) ? 48 : 32;
  __shared__ float s_win[66][8];
  __shared__ float s_wc[48][4];
  __shared__ float s_wout[8][16];
  __shared__ float s_nw[16];
  __shared__ float s_misc[8];
  __shared__ float s_slab[WCH*SLABF];   // per-wave: X[64][16] B[64][16] CF[64][2]

  int tid = threadIdx.x, lane = tid & 63, wave = tid >> 6;

  for (int i = tid; i < 66*8; i += 256) s_win[i>>3][i&7] = w_in[i];
  if (tid < 48) {
    s_wc[tid][0] = w_conv[tid*3];   s_wc[tid][1] = w_conv[tid*3+1];
    s_wc[tid][2] = w_conv[tid*3+2]; s_wc[tid][3] = b_conv[tid];
  }
  if (tid < 128) s_wout[tid>>4][tid&15] = w_out[tid];
  if (tid < 16)  s_nw[tid] = norm_w[tid];
  if (tid < 2) {
    s_misc[tid]   = -__expf(A_log[tid]);
    s_misc[2+tid] = dt_bias[tid];
    s_misc[4+tid] = Dvec[tid];
  }
  __syncthreads();

  auto dot8 = [&](const float* uu, int row) -> float {
    const float4* wr = (const float4*)s_win[row];
    float4 w0 = wr[0], w1 = wr[1];
    return uu[0]*w0.x + uu[1]*w0.y + uu[2]*w0.z + uu[3]*w0.w
         + uu[4]*w1.x + uu[5]*w1.y + uu[6]*w1.z + uu[7]*w1.w;
  };

  int b   = blockIdx.x >> 6;
  int chB = (blockIdx.x & 63)*WCH + wave;
  long cg = (long)b*NCH + chB;
  int l0  = chB*CQ;
  long pos = (long)b*SL + l0 + lane;

  float u[8];
  { const float* up = g0 + pos*8;
    float4 a = *(const float4*)up, c = *(const float4*)(up+4);
    u[0]=a.x;u[1]=a.y;u[2]=a.z;u[3]=a.w;u[4]=c.x;u[5]=c.y;u[6]=c.z;u[7]=c.w; }

  float sv[4] = {0.f,0.f,0.f,0.f};
  if constexpr (PASS==1) {
    float4 t = *(const float4*)(Stin + cg*256 + lane*4);
    sv[0]=t.x; sv[1]=t.y; sv[2]=t.z; sv[3]=t.w;
  }

  // ---- halo pre-values in registers ----
  float hA, hB = 0.f;
  {
    int pA = lane >> 5, jA = lane & 31;
    int hlA = l0 - 2 + pA;
    bool okA = (hlA >= 0);
    const float* hp2 = g0 + ((long)b*SL + (okA ? hlA : 0))*8;
    float4 a = *(const float4*)hp2, c = *(const float4*)(hp2+4);
    float uA[8] = {a.x,a.y,a.z,a.w,c.x,c.y,c.z,c.w};
    hA = okA ? dot8(uA, 16+jA) : 0.f;
    if constexpr (PASS==1) {
      int pB = (lane >> 4) & 1, jB = 32 + (lane & 15);
      int hlB = l0 - 2 + pB;
      bool okB = (hlB >= 0);
      const float* hq = g0 + ((long)b*SL + (okB ? hlB : 0))*8;
      float4 a2 = *(const float4*)hq, c2 = *(const float4*)(hq+4);
      float uB[8] = {a2.x,a2.y,a2.z,a2.w,c2.x,c2.y,c2.z,c2.w};
      hB = okB ? dot8(uB, 16+jB) : 0.f;
    }
  }

  // ---- in-proj + causal conv + silu ----
  float xv[16], Bv[16];
  float Cr[(PASS==1) ? 16 : 1];
  #pragma unroll
  for (int jb = 0; jb < JMAX/8; ++jb) {
    float pr[8];
    #pragma unroll
    for (int jj = 0; jj < 8; ++jj) pr[jj] = dot8(u, 16 + jb*8 + jj);
    #pragma unroll
    for (int jj = 0; jj < 8; ++jj) {
      int j = jb*8 + jj;
      float pm1 = __shfl_up(pr[jj], 1);
      float pm2 = __shfl_up(pr[jj], 2);
      float h0j = (j < 32) ? rl(hA, j)      : rl(hB, j-32);
      float h1j = (j < 32) ? rl(hA, 32+j)   : rl(hB, 16+(j-32));
      pm1 = (lane == 0) ? h1j : pm1;
      pm2 = (lane == 0) ? h0j : ((lane == 1) ? h1j : pm2);
      float4 wc = *(const float4*)s_wc[j];
      float a = wc.w + pm2*wc.x + pm1*wc.y + pr[jj]*wc.z;
      float s = a * sigu(a);
      if (j < 16) xv[j] = s;
      else if (j < 32) Bv[j-16] = s;
      else { if constexpr (PASS==1) Cr[j-32] = s; }
    }
  }

  // ---- dt + cumsum prefix ----
  float dt0 = softplusf(dot8(u, 64) + s_misc[2]);
  float dt1 = softplusf(dot8(u, 65) + s_misc[3]);
  float c0 = s_misc[0]*dt0, c1 = s_misc[1]*dt1;
  #pragma unroll
  for (int off = 1; off < 64; off <<= 1) {
    float t0 = __shfl_up(c0, off), t1 = __shfl_up(c1, off);
    if (lane >= off) { c0 += t0; c1 += t1; }
  }
  float ce0 = __expf(c0), ce1 = __expf(c1);
  float cf0 = __expf(-c0)*dt0, cf1 = __expf(-c1)*dt1;
  float cee0 = rl(ce0, 63), cee1 = rl(ce1, 63);

  // ---- write per-wave slab: X | B | CF (frees Bv; xv consumed at y-init) ----
  float* wSX = &s_slab[wave*SLABF];
  float* wSB = wSX + 1024;
  float* wCF = wSB + 1024;
  { float* px = wSX + lane*16;
    *(float4*)(px)    = make_float4(xv[0],xv[1],xv[2],xv[3]);
    *(float4*)(px+4)  = make_float4(xv[4],xv[5],xv[6],xv[7]);
    *(float4*)(px+8)  = make_float4(xv[8],xv[9],xv[10],xv[11]);
    *(float4*)(px+12) = make_float4(xv[12],xv[13],xv[14],xv[15]);
    float* pb = wSB + lane*16;
    *(float4*)(pb)    = make_float4(Bv[0],Bv[1],Bv[2],Bv[3]);
    *(float4*)(pb+4)  = make_float4(Bv[4],Bv[5],Bv[6],Bv[7]);
    *(float4*)(pb+8)  = make_float4(Bv[8],Bv[9],Bv[10],Bv[11]);
    *(float4*)(pb+12) = make_float4(Bv[12],Bv[13],Bv[14],Bv[15]);
    *(float2*)(wCF + lane*2) = make_float2(cf0, cf1);
  }
  __builtin_amdgcn_wave_barrier();

  if constexpr (PASS==0) {
    // lane = hp*4 + nb ; accumulate Sc[h][p][nb*4..+3] = cee_h * sum_s cf_s x_s[hp] B_s
    int hp = lane >> 2, nb = lane & 3, h = hp >> 3;
    float a0=0.f, a1=0.f, a2=0.f, a3=0.f;
    const float* pX = wSX + hp;
    const float* pC = wCF + h;
    const float* pB = wSB + nb*4;
    #pragma unroll 4
    for (int s = 0; s < CQ; ++s) {
      float t = pC[0] * pX[0];
      float4 B4 = *(const float4*)pB;
      a0 += t*B4.x; a1 += t*B4.y; a2 += t*B4.z; a3 += t*B4.w;
      pX += 16; pC += 2; pB += 16;
    }
    float cee = h ? cee1 : cee0;
    *(float4*)(Sc + cg*256 + hp*16 + nb*4) = make_float4(cee*a0,cee*a1,cee*a2,cee*a3);
    if (lane == 0) { Pc[cg*2] = cee0; Pc[cg*2+1] = cee1; }
  } else {
    // ---- y init: D*x + ce * (C . state) ; consumes xv and sv ----
    float D0 = s_misc[4], D1 = s_misc[5];
    v2f y2[8];
    #pragma unroll
    for (int hp = 0; hp < 16; ++hp) {
      float a = 0.f;
      #pragma unroll
      for (int n = 0; n < 16; ++n) {
        int idx = hp*16 + n;
        a += Cr[n] * rl(sv[idx & 3], idx >> 2);
      }
      float val = ((hp < 8) ? D0 : D1)*xv[hp] + ((hp < 8) ? ce0 : ce1)*a;
      y2[hp>>1][hp&1] = val;
    }
    // ---- intra-chunk quadratic scan: LDS broadcasts, no readlane ----
    const float* pB = wSB;
    const float* pX = wSX;
    const float* pC = wCF;
    #pragma unroll 2
    for (int s = 0; s < CQ; ++s) {
      float4 b0 = *(const float4*)(pB), b1 = *(const float4*)(pB+4);
      float4 b2 = *(const float4*)(pB+8), b3 = *(const float4*)(pB+12);
      float a0 = Cr[0]*b0.x + Cr[1]*b0.y + Cr[2]*b0.z + Cr[3]*b0.w;
      float a1 = Cr[4]*b1.x + Cr[5]*b1.y + Cr[6]*b1.z + Cr[7]*b1.w;
      float a2 = Cr[8]*b2.x + Cr[9]*b2.y + Cr[10]*b2.z + Cr[11]*b2.w;
      float a3 = Cr[12]*b3.x + Cr[13]*b3.y + Cr[14]*b3.z + Cr[15]*b3.w;
      float gg = (a0+a1) + (a2+a3);
      float2 cfp = *(const float2*)pC;
      float wA = ce0 * (cfp.x * gg);
      float wB = ce1 * (cfp.y * gg);
      bool ok = (s <= lane);
      wA = ok ? wA : 0.f; wB = ok ? wB : 0.f;
      float4 x0 = *(const float4*)(pX), x1 = *(const float4*)(pX+4);
      float4 x2 = *(const float4*)(pX+8), x3 = *(const float4*)(pX+12);
      v2f wa2 = mkv2(wA,wA), wb2 = mkv2(wB,wB);
      y2[0] += wa2 * mkv2(x0.x,x0.y);
      y2[1] += wa2 * mkv2(x0.z,x0.w);
      y2[2] += wa2 * mkv2(x1.x,x1.y);
      y2[3] += wa2 * mkv2(x1.z,x1.w);
      y2[4] += wb2 * mkv2(x2.x,x2.y);
      y2[5] += wb2 * mkv2(x2.z,x2.w);
      y2[6] += wb2 * mkv2(x3.x,x3.y);
      y2[7] += wb2 * mkv2(x3.z,x3.w);
      pB += 16; pX += 16; pC += 2;
    }
    // ---- gate, RMS norm, out-proj, +u residual ----
    float yv[16]; float ss = 0.f;
    #pragma unroll
    for (int d = 0; d < 16; ++d) {
      float zz = dot8(u, d);
      float v = y2[d>>1][d&1] * (zz * sigu(zz));
      yv[d] = v; ss += v*v;
    }
    float scn = rsqrtf(ss*(1.f/16.f) + 1e-5f);
    { const float4* nw = (const float4*)s_nw;
      float4 n0 = nw[0], n1 = nw[1], n2 = nw[2], n3 = nw[3];
      yv[0]*=scn*n0.x; yv[1]*=scn*n0.y; yv[2]*=scn*n0.z; yv[3]*=scn*n0.w;
      yv[4]*=scn*n1.x; yv[5]*=scn*n1.y; yv[6]*=scn*n1.z; yv[7]*=scn*n1.w;
      yv[8]*=scn*n2.x; yv[9]*=scn*n2.y; yv[10]*=scn*n2.z; yv[11]*=scn*n2.w;
      yv[12]*=scn*n3.x; yv[13]*=scn*n3.y; yv[14]*=scn*n3.z; yv[15]*=scn*n3.w; }
    float og[8];
    #pragma unroll
    for (int g = 0; g < 8; ++g) {
      const float4* wr = (const float4*)s_wout[g];
      float4 w0 = wr[0], w1 = wr[1], w2 = wr[2], w3 = wr[3];
      float a = u[g];
      a += yv[0]*w0.x + yv[1]*w0.y + yv[2]*w0.z + yv[3]*w0.w;
      a += yv[4]*w1.x + yv[5]*w1.y + yv[6]*w1.z + yv[7]*w1.w;
      a += yv[8]*w2.x + yv[9]*w2.y + yv[10]*w2.z + yv[11]*w2.w;
      a += yv[12]*w3.x + yv[13]*w3.y + yv[14]*w3.z + yv[15]*w3.w;
      og[g] = a;
    }
    float* gp = gf + pos*8;
    *(float4*)gp     = make_float4(og[0],og[1],og[2],og[3]);
    *(float4*)(gp+4) = make_float4(og[4],og[5],og[6],og[7]);
  }
}

__global__ __launch_bounds__(256) void k_scan(
    const float* __restrict__ Sc, const float* __restrict__ Pc,
    float* __restrict__ Stin)
{
  int b = blockIdx.x;
  int tid = threadIdx.x;
  int h = tid >> 7;
  float st = 0.f;
  long base = (long)b * NCH;
  #pragma unroll 8
  for (int c = 0; c < NCH; ++c) {
    Stin[(base + c)*256 + tid] = st;
    st = st * Pc[(base + c)*2 + h] + Sc[(base + c)*256 + tid];
  }
}

__global__ __launch_bounds__(256) void k_detok(
    const float* __restrict__ x, const float* __restrict__ gf,
    const float* __restrict__ w_detok, const float* __restrict__ b_detok,
    float* __restrict__ out)
{
  __shared__ float s_wd[NC][8];
  __shared__ float s_bd[NC];
  for (int i = threadIdx.x; i < NC*8; i += 256) s_wd[i>>3][i&7] = w_detok[i];
  if (threadIdx.x < NC) s_bd[threadIdx.x] = b_detok[threadIdx.x];
  __syncthreads();
  long idx = (long)blockIdx.x * 256 + threadIdx.x;
  int b = (int)(idx >> 14);
  int l = (int)(idx & (SL-1));
  float gv[8];
  const float* gp = gf + idx*8;
  { float4 a = *(const float4*)gp, c = *(const float4*)(gp+4);
    gv[0]=a.x;gv[1]=a.y;gv[2]=a.z;gv[3]=a.w;gv[4]=c.x;gv[5]=c.y;gv[6]=c.z;gv[7]=c.w; }
  const float* xp = x + (long)b*NC*HW + l;
  float* op = out + (long)b*NC*HW + l;
  #pragma unroll 4
  for (int c = 0; c < NC; ++c) {
    const float4* wr = (const float4*)s_wd[c];
    float4 w0 = wr[0], w1 = wr[1];
    float a = s_bd[c] + xp[(long)c*HW];
    a += gv[0]*w0.x + gv[1]*w0.y + gv[2]*w0.z + gv[3]*w0.w;
    a += gv[4]*w1.x + gv[5]*w1.y + gv[6]*w1.z + gv[7]*w1.w;
    op[(long)c*HW] = a;
  }
}
} // namespace

extern "C" void kernel_launch(void* const* d_in, const int* in_sizes, int n_in,
                              void* d_out, int out_size, void* d_ws, size_t ws_size,
                              hipStream_t stream)
{
  const float* x       = (const float*)d_in[0];
  const float* w_tok   = (const float*)d_in[1];
  const float* b_tok   = (const float*)d_in[2];
  const float* w_detok = (const float*)d_in[3];
  const float* b_detok = (const float*)d_in[4];
  const float* w_in    = (const float*)d_in[5];
  const float* w_conv  = (const float*)d_in[6];
  const float* b_conv  = (const float*)d_in[7];
  const float* dt_bias = (const float*)d_in[8];
  const float* A_log   = (const float*)d_in[9];
  const float* Dvec    = (const float*)d_in[10];
  const float* norm_w  = (const float*)d_in[11];
  const float* w_out   = (const float*)d_in[12];
  float* out = (float*)d_out;

  float* ws   = (float*)d_ws;
  float* g0   = ws;
  float* gf   = g0 + (long)NB*SL*NG;
  float* Sc   = gf + (long)NB*SL*NG;
  float* Pc   = Sc + (long)NB*NCH*256;
  float* Stin = Pc + (long)NB*NCH*2;

  k_tok<<<NB*SL/256, 256, 0, stream>>>(x, w_tok, b_tok, g0);
  k_chunk<0><<<NB*NCH/WCH, 256, 0, stream>>>(g0, w_in, w_conv, b_conv, dt_bias,
                                             A_log, Dvec, norm_w, w_out,
                                             Sc, Pc, nullptr, nullptr);
  k_scan<<<NB, 256, 0, stream>>>(Sc, Pc, Stin);
  k_chunk<1><<<NB*NCH/WCH, 256, 0, stream>>>(g0, w_in, w_conv, b_conv, dt_bias,
                                             A_log, Dvec, norm_w, w_out,
                                             Sc, Pc, Stin, gf);
  k_detok<<<NB*SL/256, 256, 0, stream>>>(x, gf, w_detok, b_detok, out);
}

// Round 8
// 106.487 us; speedup vs baseline: 1.5339x; 1.2189x over previous
//
#include <hip/hip_runtime.h>

namespace {
constexpr int NB   = 16;
constexpr int NC   = 64;
constexpr int HW   = 128*128;
constexpr int SL   = 16384;
constexpr int CQ   = 64;
constexpr int NCH  = SL/CQ;   // 256
constexpr int WCH  = 4;       // chunks (waves) per block

typedef short short8 __attribute__((ext_vector_type(8)));   // 8 bf16 (4 VGPR)
typedef float f32x4  __attribute__((ext_vector_type(4)));

__device__ __forceinline__ float frcp(float x){ return __builtin_amdgcn_rcpf(x); }
__device__ __forceinline__ float rl(float v, int s){
  return __int_as_float(__builtin_amdgcn_readlane(__float_as_int(v), s));
}
__device__ __forceinline__ float sigu(float a){ return frcp(1.0f + __expf(-a)); }
__device__ __forceinline__ float softplusf(float a){
  return fmaxf(a, 0.f) + __logf(1.f + __expf(-fabsf(a)));
}
// f32 -> bf16 (RNE) bits
__device__ __forceinline__ unsigned bfr(float x){
  unsigned u = __float_as_uint(x);
  u = u + 0x7FFF + ((u>>16)&1);
  return u>>16;
}
__device__ __forceinline__ unsigned pk2(float a, float b){
  return (bfr(a)&0xFFFFu) | (bfr(b)<<16);
}
union CV8 { unsigned u[4]; short8 s; };

__global__ __launch_bounds__(256) void k_tok(
    const float* __restrict__ x, const float* __restrict__ w_tok,
    const float* __restrict__ b_tok, float* __restrict__ g0)
{
  __shared__ float s_wt[NC][8];
  __shared__ float s_bt[8];
  for (int i = threadIdx.x; i < NC*8; i += 256) s_wt[i>>3][i&7] = w_tok[(i&7)*NC + (i>>3)];
  if (threadIdx.x < 8) s_bt[threadIdx.x] = b_tok[threadIdx.x];
  __syncthreads();
  long idx = (long)blockIdx.x * 256 + threadIdx.x;
  int b = (int)(idx >> 14);
  int l = (int)(idx & (SL-1));
  float acc[8];
  #pragma unroll
  for (int g = 0; g < 8; ++g) acc[g] = s_bt[g];
  const float* xp = x + (long)b*NC*HW + l;
  #pragma unroll 8
  for (int c = 0; c < NC; ++c) {
    float v = xp[(long)c*HW];
    const float4* wr = (const float4*)s_wt[c];
    float4 w0 = wr[0], w1 = wr[1];
    acc[0] += v*w0.x; acc[1] += v*w0.y; acc[2] += v*w0.z; acc[3] += v*w0.w;
    acc[4] += v*w1.x; acc[5] += v*w1.y; acc[6] += v*w1.z; acc[7] += v*w1.w;
  }
  float* gp = g0 + idx*8;
  *(float4*)gp     = make_float4(acc[0],acc[1],acc[2],acc[3]);
  *(float4*)(gp+4) = make_float4(acc[4],acc[5],acc[6],acc[7]);
}

// PASS 0: Sc (chunk state contribution, via MFMA) + Pc.
// PASS 1: outputs -> gf (scan via MFMA on bf16 score matrix).
template<int PASS>
__global__ __launch_bounds__(256)
void k_chunk(
    const float* __restrict__ g0, const float* __restrict__ w_in,
    const float* __restrict__ w_conv, const float* __restrict__ b_conv,
    const float* __restrict__ dt_bias, const float* __restrict__ A_log,
    const float* __restrict__ Dvec, const float* __restrict__ norm_w,
    const float* __restrict__ w_out,
    float* __restrict__ Sc, float* __restrict__ Pc,
    const float* __restrict__ Stin, float* __restrict__ gf)
{
  constexpr int JMAX = (PASS==1) ? 48 : 32;
  // per-wave LDS bytes:
  // PASS1: [0,8192) union{ B(bf16 [64][16]) @0, C @2048 } -> M(bf16 [64][64]) -> ytr(f32 [64][24])
  //        [8192,10240) X' bf16 [16][64] swizzled ; [10240,10752) ce f32 [2][64]
  // PASS0: [0,2048) BT bf16 [16][64] swizzled ; [2048,4096) X' bf16 [16][64] swizzled
  constexpr int PW = (PASS==1) ? 10752 : 4096;
  __shared__ float s_win[66][8];
  __shared__ float s_wc[48][4];
  __shared__ float s_wout[8][16];
  __shared__ float s_nw[16];
  __shared__ float s_misc[8];
  __shared__ char  s_big[WCH*PW];

  int tid = threadIdx.x, lane = tid & 63, wave = tid >> 6;
  int c15 = lane & 15, lg = lane >> 4;

  for (int i = tid; i < 66*8; i += 256) s_win[i>>3][i&7] = w_in[i];
  if (tid < 48) {
    s_wc[tid][0] = w_conv[tid*3];   s_wc[tid][1] = w_conv[tid*3+1];
    s_wc[tid][2] = w_conv[tid*3+2]; s_wc[tid][3] = b_conv[tid];
  }
  if (tid < 128) s_wout[tid>>4][tid&15] = w_out[tid];
  if (tid < 16)  s_nw[tid] = norm_w[tid];
  if (tid < 2) {
    s_misc[tid]   = -__expf(A_log[tid]);
    s_misc[2+tid] = dt_bias[tid];
    s_misc[4+tid] = Dvec[tid];
  }
  __syncthreads();

  auto dot8 = [&](const float* uu, int row) -> float {
    const float4* wr = (const float4*)s_win[row];
    float4 w0 = wr[0], w1 = wr[1];
    return uu[0]*w0.x + uu[1]*w0.y + uu[2]*w0.z + uu[3]*w0.w
         + uu[4]*w1.x + uu[5]*w1.y + uu[6]*w1.z + uu[7]*w1.w;
  };

  int b   = blockIdx.x >> 6;
  int chB = (blockIdx.x & 63)*WCH + wave;
  long cg = (long)b*NCH + chB;
  int l0  = chB*CQ;
  long pos = (long)b*SL + l0 + lane;
  char* WR = &s_big[wave*PW];

  float u[8];
  { const float* up = g0 + pos*8;
    float4 a = *(const float4*)up, c = *(const float4*)(up+4);
    u[0]=a.x;u[1]=a.y;u[2]=a.z;u[3]=a.w;u[4]=c.x;u[5]=c.y;u[6]=c.z;u[7]=c.w; }

  // ---- halo pre-values in registers ----
  float hA, hB = 0.f;
  {
    int pA = lane >> 5, jA = lane & 31;
    int hlA = l0 - 2 + pA;
    bool okA = (hlA >= 0);
    const float* hp2 = g0 + ((long)b*SL + (okA ? hlA : 0))*8;
    float4 a = *(const float4*)hp2, c = *(const float4*)(hp2+4);
    float uA[8] = {a.x,a.y,a.z,a.w,c.x,c.y,c.z,c.w};
    hA = okA ? dot8(uA, 16+jA) : 0.f;
    if constexpr (PASS==1) {
      int pB = (lane >> 4) & 1, jB = 32 + (lane & 15);
      int hlB = l0 - 2 + pB;
      bool okB = (hlB >= 0);
      const float* hq = g0 + ((long)b*SL + (okB ? hlB : 0))*8;
      float4 a2 = *(const float4*)hq, c2 = *(const float4*)(hq+4);
      float uB[8] = {a2.x,a2.y,a2.z,a2.w,c2.x,c2.y,c2.z,c2.w};
      hB = okB ? dot8(uB, 16+jB) : 0.f;
    }
  }

  // ---- in-proj + causal conv + silu ----
  float xv[16], Bv[16];
  float Cr[(PASS==1) ? 16 : 1];
  #pragma unroll
  for (int jb = 0; jb < JMAX/8; ++jb) {
    float pr[8];
    #pragma unroll
    for (int jj = 0; jj < 8; ++jj) pr[jj] = dot8(u, 16 + jb*8 + jj);
    #pragma unroll
    for (int jj = 0; jj < 8; ++jj) {
      int j = jb*8 + jj;
      float pm1 = __shfl_up(pr[jj], 1);
      float pm2 = __shfl_up(pr[jj], 2);
      float h0j = (j < 32) ? rl(hA, j)      : rl(hB, j-32);
      float h1j = (j < 32) ? rl(hA, 32+j)   : rl(hB, 16+(j-32));
      pm1 = (lane == 0) ? h1j : pm1;
      pm2 = (lane == 0) ? h0j : ((lane == 1) ? h1j : pm2);
      float4 wc = *(const float4*)s_wc[j];
      float a = wc.w + pm2*wc.x + pm1*wc.y + pr[jj]*wc.z;
      float s = a * sigu(a);
      if (j < 16) xv[j] = s;
      else if (j < 32) Bv[j-16] = s;
      else { if constexpr (PASS==1) Cr[j-32] = s; }
    }
  }

  // ---- dt + cumsum prefix ----
  float dt0 = softplusf(dot8(u, 64) + s_misc[2]);
  float dt1 = softplusf(dot8(u, 65) + s_misc[3]);
  float c0 = s_misc[0]*dt0, c1 = s_misc[1]*dt1;
  #pragma unroll
  for (int off = 1; off < 64; off <<= 1) {
    float t0 = __shfl_up(c0, off), t1 = __shfl_up(c1, off);
    if (lane >= off) { c0 += t0; c1 += t1; }
  }
  float ce0 = __expf(c0), ce1 = __expf(c1);
  float cf0 = __expf(-c0)*dt0, cf1 = __expf(-c1)*dt1;
  float cee0 = rl(ce0, 63), cee1 = rl(ce1, 63);

  // ---- X' slab (bf16 [16][64], row-XOR swizzle): X'[s][hp] = cf_h[s]*x[s][hp]
  char* xp = WR + ((PASS==1) ? 8192 : 2048);
  #pragma unroll
  for (int hp = 0; hp < 16; ++hp) {
    float cfh = (hp < 8) ? cf0 : cf1;
    *(short*)(xp + hp*128 + ((lane*2) ^ ((hp&7)<<4))) = (short)bfr(cfh*xv[hp]);
  }

  if constexpr (PASS==0) {
    // BT bf16 [16][64] swizzled: BT[n][s] = B[s][n]
    char* BT = WR;
    #pragma unroll
    for (int n = 0; n < 16; ++n)
      *(short*)(BT + n*128 + ((lane*2) ^ ((n&7)<<4))) = (short)bfr(Bv[n]);
    __builtin_amdgcn_wave_barrier();
    __builtin_amdgcn_sched_barrier(0);
    // S[hp][n] = cee_h * sum_s X'[s][hp] * B[s][n]   (A = X'^T, B-op = B)
    f32x4 acc = {0.f,0.f,0.f,0.f};
    #pragma unroll
    for (int kb = 0; kb < 2; ++kb) {
      int cb = (64*kb + 16*lg) ^ ((c15&7)<<4);
      short8 Af = *(const short8*)(xp + c15*128 + cb);
      short8 Bf = *(const short8*)(BT + c15*128 + cb);
      acc = __builtin_amdgcn_mfma_f32_16x16x32_bf16(Af, Bf, acc, 0, 0, 0);
    }
    float cee = (lg < 2) ? cee0 : cee1;   // hp = 4*lg+r : head = hp<8 <=> lg<2
    #pragma unroll
    for (int r = 0; r < 4; ++r)
      Sc[cg*256 + (4*lg+r)*16 + c15] = cee*acc[r];
    if (lane == 0) { Pc[cg*2] = cee0; Pc[cg*2+1] = cee1; }
  } else {
    char* uB  = WR;          // bf16 [64][16] rows 32B
    char* uC  = WR + 2048;
    char* Mb  = WR;          // bf16 [64][64] rows 128B, swizzled (after B,C dead)
    char* ytr = WR;          // f32 [64][24] rows 96B (after M dead)
    char* ceB = WR + 10240;  // f32 [2][64]
    // B,C slabs
    { CV8 w;
      w.u[0]=pk2(Bv[0],Bv[1]);  w.u[1]=pk2(Bv[2],Bv[3]);
      w.u[2]=pk2(Bv[4],Bv[5]);  w.u[3]=pk2(Bv[6],Bv[7]);
      *(short8*)(uB + lane*32) = w.s;
      w.u[0]=pk2(Bv[8],Bv[9]);  w.u[1]=pk2(Bv[10],Bv[11]);
      w.u[2]=pk2(Bv[12],Bv[13]);w.u[3]=pk2(Bv[14],Bv[15]);
      *(short8*)(uB + lane*32 + 16) = w.s;
      w.u[0]=pk2(Cr[0],Cr[1]);  w.u[1]=pk2(Cr[2],Cr[3]);
      w.u[2]=pk2(Cr[4],Cr[5]);  w.u[3]=pk2(Cr[6],Cr[7]);
      *(short8*)(uC + lane*32) = w.s;
      w.u[0]=pk2(Cr[8],Cr[9]);  w.u[1]=pk2(Cr[10],Cr[11]);
      w.u[2]=pk2(Cr[12],Cr[13]);w.u[3]=pk2(Cr[14],Cr[15]);
      *(short8*)(uC + lane*32 + 16) = w.s;
    }
    *(float*)(ceB + lane*4)       = ce0;
    *(float*)(ceB + 256 + lane*4) = ce1;
    __builtin_amdgcn_wave_barrier();
    __builtin_amdgcn_sched_barrier(0);

    // fragments: row = c15 (within tile), k = n = 8*lg + i  (lg>=2 -> zero pad)
    short8 zero8 = {0,0,0,0,0,0,0,0};
    f32x4  zero4 = {0.f,0.f,0.f,0.f};
    short8 Cfr[4], Bfr[4];
    #pragma unroll
    for (int tt = 0; tt < 4; ++tt) {
      Cfr[tt] = zero8; Bfr[tt] = zero8;
      if (lg < 2) {
        Cfr[tt] = *(const short8*)(uC + (16*tt + c15)*32 + 16*lg);
        Bfr[tt] = *(const short8*)(uB + (16*tt + c15)*32 + 16*lg);
      }
    }
    // incoming-state fragment (B-op: [k=n][col=hp] = St[hp][n]) from global
    short8 stf = zero8;
    if (lg < 2) {
      const float* sp = Stin + cg*256 + c15*16 + 8*lg;
      float4 s0 = *(const float4*)sp, s1 = *(const float4*)(sp+4);
      CV8 cv;
      cv.u[0]=pk2(s0.x,s0.y); cv.u[1]=pk2(s0.z,s0.w);
      cv.u[2]=pk2(s1.x,s1.y); cv.u[3]=pk2(s1.z,s1.w);
      stf = cv.s;
    }
    // init: acc[tt] = C_tile_tt . St^T   (D: row=t, col=hp)
    f32x4 acc[4];
    #pragma unroll
    for (int tt = 0; tt < 4; ++tt)
      acc[tt] = __builtin_amdgcn_mfma_f32_16x16x32_bf16(Cfr[tt], stf, zero4, 0,0,0);

    // G' = B.C^T per tile pair; mask; write M (bf16, swizzled). Also zero-pad
    // tiles (tt,tt+1) for tt=0,2 (read by K=32 Y-MFMA but causally zero).
    #pragma unroll
    for (int tt = 0; tt < 4; ++tt) {
      int t  = 16*tt + c15;
      int sw = (t&7)<<4;
      #pragma unroll
      for (int ts = 0; ts < 4; ++ts) {
        if (ts <= tt) {
          f32x4 gA = __builtin_amdgcn_mfma_f32_16x16x32_bf16(Bfr[ts], Cfr[tt], zero4, 0,0,0);
          if (ts == tt) {
            #pragma unroll
            for (int r = 0; r < 4; ++r)
              gA[r] = (4*lg + r <= c15) ? gA[r] : 0.f;
          }
          uint2 wv; wv.x = pk2(gA[0],gA[1]); wv.y = pk2(gA[2],gA[3]);
          *(uint2*)(Mb + t*128 + ((32*ts + 8*lg) ^ sw)) = wv;
        }
      }
      if (tt == 0 || tt == 2) {
        uint2 zv; zv.x = 0u; zv.y = 0u;
        *(uint2*)(Mb + t*128 + ((32*(tt+1) + 8*lg) ^ sw)) = zv;
      }
    }
    __builtin_amdgcn_wave_barrier();
    __builtin_amdgcn_sched_barrier(0);

    // Y accumulate: acc[tt] += M_rows_tt . X'
    short8 Xf[2];
    #pragma unroll
    for (int kb = 0; kb < 2; ++kb)
      Xf[kb] = *(const short8*)(xp + c15*128 + ((64*kb + 16*lg) ^ ((c15&7)<<4)));
    #pragma unroll
    for (int tt = 0; tt < 4; ++tt) {
      int t = 16*tt + c15, sw = (t&7)<<4;
      {
        short8 Mf = *(const short8*)(Mb + t*128 + ((16*lg) ^ sw));
        acc[tt] = __builtin_amdgcn_mfma_f32_16x16x32_bf16(Mf, Xf[0], acc[tt], 0,0,0);
      }
      if (tt >= 2) {
        short8 Mf = *(const short8*)(Mb + t*128 + ((64 + 16*lg) ^ sw));
        acc[tt] = __builtin_amdgcn_mfma_f32_16x16x32_bf16(Mf, Xf[1], acc[tt], 0,0,0);
      }
    }
    // merge ce_h[t] and transpose via LDS ([64][24] f32)
    int hh = (c15 < 8) ? 0 : 1;
    #pragma unroll
    for (int tt = 0; tt < 4; ++tt) {
      float4 cev = *(const float4*)(ceB + hh*256 + (16*tt + 4*lg)*4);
      float cva[4] = {cev.x, cev.y, cev.z, cev.w};
      #pragma unroll
      for (int r = 0; r < 4; ++r)
        *(float*)(ytr + (16*tt + 4*lg + r)*96 + c15*4) = cva[r]*acc[tt][r];
    }
    __builtin_amdgcn_wave_barrier();
    __builtin_amdgcn_sched_barrier(0);

    // ---- epilogue (lane = t): +D*x, gate, RMS, out-proj, +u, store ----
    float yr[16];
    #pragma unroll
    for (int i = 0; i < 4; ++i) {
      float4 q = *(const float4*)(ytr + lane*96 + 16*i);
      yr[4*i] = q.x; yr[4*i+1] = q.y; yr[4*i+2] = q.z; yr[4*i+3] = q.w;
    }
    float D0 = s_misc[4], D1 = s_misc[5];
    float yv[16]; float ss = 0.f;
    #pragma unroll
    for (int d = 0; d < 16; ++d) {
      float base = yr[d] + ((d < 8) ? D0 : D1)*xv[d];
      float zz = dot8(u, d);
      float v = base * (zz * sigu(zz));
      yv[d] = v; ss += v*v;
    }
    float scn = rsqrtf(ss*(1.f/16.f) + 1e-5f);
    { const float4* nw = (const float4*)s_nw;
      float4 n0 = nw[0], n1 = nw[1], n2 = nw[2], n3 = nw[3];
      yv[0]*=scn*n0.x; yv[1]*=scn*n0.y; yv[2]*=scn*n0.z; yv[3]*=scn*n0.w;
      yv[4]*=scn*n1.x; yv[5]*=scn*n1.y; yv[6]*=scn*n1.z; yv[7]*=scn*n1.w;
      yv[8]*=scn*n2.x; yv[9]*=scn*n2.y; yv[10]*=scn*n2.z; yv[11]*=scn*n2.w;
      yv[12]*=scn*n3.x; yv[13]*=scn*n3.y; yv[14]*=scn*n3.z; yv[15]*=scn*n3.w; }
    float og[8];
    #pragma unroll
    for (int g = 0; g < 8; ++g) {
      const float4* wr = (const float4*)s_wout[g];
      float4 w0 = wr[0], w1 = wr[1], w2 = wr[2], w3 = wr[3];
      float a = u[g];
      a += yv[0]*w0.x + yv[1]*w0.y + yv[2]*w0.z + yv[3]*w0.w;
      a += yv[4]*w1.x + yv[5]*w1.y + yv[6]*w1.z + yv[7]*w1.w;
      a += yv[8]*w2.x + yv[9]*w2.y + yv[10]*w2.z + yv[11]*w2.w;
      a += yv[12]*w3.x + yv[13]*w3.y + yv[14]*w3.z + yv[15]*w3.w;
      og[g] = a;
    }
    float* gp = gf + pos*8;
    *(float4*)gp     = make_float4(og[0],og[1],og[2],og[3]);
    *(float4*)(gp+4) = make_float4(og[4],og[5],og[6],og[7]);
  }
}

__global__ __launch_bounds__(256) void k_scan(
    const float* __restrict__ Sc, const float* __restrict__ Pc,
    float* __restrict__ Stin)
{
  int b = blockIdx.x;
  int tid = threadIdx.x;           // hp*16 + n
  int h = tid >> 7;
  float st = 0.f;
  long base = (long)b * NCH;
  #pragma unroll 8
  for (int c = 0; c < NCH; ++c) {
    Stin[(base + c)*256 + tid] = st;
    st = st * Pc[(base + c)*2 + h] + Sc[(base + c)*256 + tid];
  }
}

__global__ __launch_bounds__(256) void k_detok(
    const float* __restrict__ x, const float* __restrict__ gf,
    const float* __restrict__ w_detok, const float* __restrict__ b_detok,
    float* __restrict__ out)
{
  __shared__ float s_wd[NC][8];
  __shared__ float s_bd[NC];
  for (int i = threadIdx.x; i < NC*8; i += 256) s_wd[i>>3][i&7] = w_detok[i];
  if (threadIdx.x < NC) s_bd[threadIdx.x] = b_detok[threadIdx.x];
  __syncthreads();
  long idx = (long)blockIdx.x * 256 + threadIdx.x;
  int b = (int)(idx >> 14);
  int l = (int)(idx & (SL-1));
  float gv[8];
  const float* gp = gf + idx*8;
  { float4 a = *(const float4*)gp, c = *(const float4*)(gp+4);
    gv[0]=a.x;gv[1]=a.y;gv[2]=a.z;gv[3]=a.w;gv[4]=c.x;gv[5]=c.y;gv[6]=c.z;gv[7]=c.w; }
  const float* xp = x + (long)b*NC*HW + l;
  float* op = out + (long)b*NC*HW + l;
  #pragma unroll 4
  for (int c = 0; c < NC; ++c) {
    const float4* wr = (const float4*)s_wd[c];
    float4 w0 = wr[0], w1 = wr[1];
    float a = s_bd[c] + xp[(long)c*HW];
    a += gv[0]*w0.x + gv[1]*w0.y + gv[2]*w0.z + gv[3]*w0.w;
    a += gv[4]*w1.x + gv[5]*w1.y + gv[6]*w1.z + gv[7]*w1.w;
    op[(long)c*HW] = a;
  }
}
} // namespace

extern "C" void kernel_launch(void* const* d_in, const int* in_sizes, int n_in,
                              void* d_out, int out_size, void* d_ws, size_t ws_size,
                              hipStream_t stream)
{
  const float* x       = (const float*)d_in[0];
  const float* w_tok   = (const float*)d_in[1];
  const float* b_tok   = (const float*)d_in[2];
  const float* w_detok = (const float*)d_in[3];
  const float* b_detok = (const float*)d_in[4];
  const float* w_in    = (const float*)d_in[5];
  const float* w_conv  = (const float*)d_in[6];
  const float* b_conv  = (const float*)d_in[7];
  const float* dt_bias = (const float*)d_in[8];
  const float* A_log   = (const float*)d_in[9];
  const float* Dvec    = (const float*)d_in[10];
  const float* norm_w  = (const float*)d_in[11];
  const float* w_out   = (const float*)d_in[12];
  float* out = (float*)d_out;

  float* ws   = (float*)d_ws;
  float* g0   = ws;
  float* gf   = g0 + (long)NB*SL*8;
  float* Sc   = gf + (long)NB*SL*8;
  float* Pc   = Sc + (long)NB*NCH*256;
  float* Stin = Pc + (long)NB*NCH*2;

  k_tok<<<NB*SL/256, 256, 0, stream>>>(x, w_tok, b_tok, g0);
  k_chunk<0><<<NB*NCH/WCH, 256, 0, stream>>>(g0, w_in, w_conv, b_conv, dt_bias,
                                             A_log, Dvec, norm_w, w_out,
                                             Sc, Pc, nullptr, nullptr);
  k_scan<<<NB, 256, 0, stream>>>(Sc, Pc, Stin);
  k_chunk<1><<<NB*NCH/WCH, 256, 0, stream>>>(g0, w_in, w_conv, b_conv, dt_bias,
                                             A_log, Dvec, norm_w, w_out,
                                             Sc, Pc, Stin, gf);
  k_detok<<<NB*SL/256, 256, 0, stream>>>(x, gf, w_detok, b_detok, out);
}